// Round 12
// baseline (256.829 us; speedup 1.0000x reference)
//
#include <hip/hip_runtime.h>

#define IMG_H 512
#define IMG_W 512
#define RPB 8             // rows per block
#define NROW (RPB + 1)    // 9 (incl. north halo)
#define NLEV 256
#define NB 32
#define NC 3
#define NYB (IMG_H / RPB) // 64
#define BINS (NC * NLEV)  // 768
#define NBLK (NB * NYB)   // 2048
#define NTHR 256
#define NWAVE (NTHR / 64) // 4

// Per-block packed partials {cnt, fqsum}: plain stores, single writer.
__device__ uint2    g_pk[NBLK * BINS];     // 12.6 MB
__device__ unsigned g_dropQ[NBLK * NC];
__device__ float    g_ent[NB * NC];
__device__ unsigned g_done = 0;            // flush-completion counter
__device__ unsigned g_done2 = 0;           // ent-completion counter

// fmodf(v+1,2)-1, branch-free, exact.
__device__ __forceinline__ float wrap1(float v) {
    float a = v + 1.0f;
    return a - 2.0f * truncf(0.5f * a) - 1.0f;
}

__device__ __forceinline__ void xform(float& r, float& g, float& bl,
                                      const float* __restrict__ p) {
    float r1 = r + (p[0] * g + p[1] * bl);
    float g1 = g + (p[2] * r1 + p[3] * bl);
    float b1 = bl + (p[4] * r1 + p[5] * g1);
    float r2 = r1 + (p[6] * g1 + p[7] * b1);
    float g2 = g1 + (p[8] * r2 + p[9] * b1);
    float b2 = b1 + (p[10] * r2 + p[11] * g2);
    r = wrap1(r2); g = wrap1(g2); bl = wrap1(b2);
}

// Residual -> ONE packed u32 LDS atomic: {count:11 | fracQ:21}. JAX
// negative-index wrap (+256) before bounds check; i0==255 frac dropped
// (tracked). Max 1024 contribs/bin/wave-channel -> no overflow.
__device__ __forceinline__ void accum(float y, float n, float w, float nw,
                                      unsigned* __restrict__ h,
                                      unsigned* __restrict__ drop) {
    float lo = fminf(n, w), hi = fmaxf(n, w);
    float pred = fminf(fmaxf(n + w - nw, lo), hi);
    float xs = (y - pred + 1.0f) * 127.5f;
    float f = floorf(xs);
    float frac = xs - f;
    int i0 = (int)f;
    unsigned fq = (unsigned)(frac * 1024.0f + 0.5f);
    int j0 = (i0 < 0) ? i0 + NLEV : i0;
    if ((unsigned)j0 < (unsigned)NLEV) {
        atomicAdd(&h[j0], (1u << 21) | fq);
        if (i0 == NLEV - 1) atomicAdd(drop, fq);
    }
}

__global__ __launch_bounds__(NTHR) void hist_ent(const float* __restrict__ x,
                                                 const float* __restrict__ params,
                                                 float* __restrict__ out) {
    __shared__ unsigned lhw[NWAVE][NC][NLEV];  // 12 KiB packed hists
    __shared__ float bnd[NWAVE][NROW][NC];     // lane-63 odd-col y per wave
    __shared__ unsigned dropw[NC];
    const int tid = threadIdx.x;
    const int b = blockIdx.x;
    const int yb = blockIdx.y;
    const int r0 = yb * RPB;
    const int wv = tid >> 6;
    const int lane = tid & 63;

    unsigned* lp = &lhw[0][0][0];
#pragma unroll
    for (int i = tid; i < NWAVE * BINS; i += NTHR) lp[i] = 0u;
    if (tid < NC) dropw[tid] = 0u;

    float p[12];
#pragma unroll
    for (int i = 0; i < 12; ++i) p[i] = params[i];

    const int hw = IMG_H * IMG_W;
    // thread owns cols {2*tid, 2*tid+1}; float2 units
    const float2* base = (const float2*)(x + (size_t)(b * 3) * hw) + tid;

    // Phase A: 27 independent float2 loads
    float a0[NROW], a1[NROW], c0[NROW], c1[NROW], e0[NROW], e1[NROW];
#pragma unroll
    for (int rr = 0; rr < NROW; ++rr) {
        if (rr > 0 || r0 > 0) {
            int ro = (r0 - 1 + rr) * (IMG_W / 2);
            float2 vr = base[ro];
            float2 vg = base[ro + hw / 2];
            float2 vb = base[ro + hw];
            a0[rr] = vr.x; a1[rr] = vr.y;
            c0[rr] = vg.x; c1[rr] = vg.y;
            e0[rr] = vb.x; e1[rr] = vb.y;
        } else {
            a0[rr] = a1[rr] = c0[rr] = c1[rr] = e0[rr] = e1[rr] = 0.0f;
        }
    }

    // Phase B: transform both columns, all rows (transform(0)==0)
#pragma unroll
    for (int rr = 0; rr < NROW; ++rr) {
        xform(a0[rr], c0[rr], e0[rr], p);
        xform(a1[rr], c1[rr], e1[rr], p);
    }

    // boundary: lane 63's odd col feeds next wave's lane 0
    if (lane == 63) {
#pragma unroll
        for (int rr = 0; rr < NROW; ++rr) {
            bnd[wv][rr][0] = a1[rr];
            bnd[wv][rr][1] = c1[rr];
            bnd[wv][rr][2] = e1[rr];
        }
    }
    __syncthreads();

    // stage prev wave's 27 boundary words with ONE ds_read; extract via
    // v_readlane (compile-time lane index) -> zero DS reads in the loop.
    const int pw = (wv > 0) ? wv - 1 : 0;
    const float* pwb = &bnd[pw][0][0];
    float bv = pwb[lane < NROW * NC ? lane : 0];
    const bool lz = (lane == 0);

#define RDL(rr, ch) __int_as_float(__builtin_amdgcn_readlane(__float_as_int(bv), (rr) * NC + (ch)))

    unsigned* h0 = &lhw[wv][0][0];
    unsigned* h1 = &lhw[wv][1][0];
    unsigned* h2 = &lhw[wv][2][0];

    // carries: north (both cols) + northwest (even col; nw of odd = n of even)
    float nA0 = a0[0], nA1 = a1[0];
    float nC0 = c0[0], nC1 = c1[0];
    float nE0 = e0[0], nE1 = e1[0];
    float nwA = __shfl_up(a1[0], 1);
    float nwC = __shfl_up(c1[0], 1);
    float nwE = __shfl_up(e1[0], 1);
    {
        float bA = (wv > 0) ? RDL(0, 0) : 0.0f;
        float bC = (wv > 0) ? RDL(0, 1) : 0.0f;
        float bE = (wv > 0) ? RDL(0, 2) : 0.0f;
        if (lz) { nwA = bA; nwC = bC; nwE = bE; }
    }

#pragma unroll
    for (int rr = 1; rr < NROW; ++rr) {
        float uA0 = a0[rr], uA1 = a1[rr];
        float uC0 = c0[rr], uC1 = c1[rr];
        float uE0 = e0[rr], uE1 = e1[rr];
        float vA = __shfl_up(uA1, 1);
        float vC = __shfl_up(uC1, 1);
        float vE = __shfl_up(uE1, 1);
        float bA = (wv > 0) ? RDL(rr, 0) : 0.0f;
        float bC = (wv > 0) ? RDL(rr, 1) : 0.0f;
        float bE = (wv > 0) ? RDL(rr, 2) : 0.0f;
        if (lz) { vA = bA; vC = bC; vE = bE; }
        // even col: west = vX, nw = nwX ; odd col: west = even cur, nw = even north
        accum(uA0, nA0, vA, nwA, h0, &dropw[0]);
        accum(uA1, nA1, uA0, nA0, h0, &dropw[0]);
        accum(uC0, nC0, vC, nwC, h1, &dropw[1]);
        accum(uC1, nC1, uC0, nC0, h1, &dropw[1]);
        accum(uE0, nE0, vE, nwE, h2, &dropw[2]);
        accum(uE1, nE1, uE0, nE0, h2, &dropw[2]);
        nwA = vA; nA0 = uA0; nA1 = uA1;
        nwC = vC; nC0 = uC0; nC1 = uC1;
        nwE = vE; nE0 = uE0; nE1 = uE1;
    }
    __syncthreads();

    // flush: unpack + sum 4 waves, ONE uint2 (8B) store per bin
    const int blk = b * NYB + yb;
    uint2* dp = g_pk + (size_t)blk * BINS;
#pragma unroll
    for (int i = tid; i < BINS; i += NTHR) {
        int c = i >> 8, bin = i & 255;
        unsigned cs = 0, qs = 0;
#pragma unroll
        for (int w2 = 0; w2 < NWAVE; ++w2) {
            unsigned v = lhw[w2][c][bin];
            cs += v >> 21;
            qs += v & 0x1FFFFFu;
        }
        dp[i] = make_uint2(cs, qs);
    }
    if (tid < NC) g_dropQ[blk * NC + tid] = dropw[tid];

    // ---- fused entropy phase ----
    __threadfence();                               // release partials
    if (tid == 0) atomicAdd(&g_done, 1u);
    if (yb >= NC) return;                          // 96 ent blocks continue

    // wait until ALL 2048 blocks have flushed (device-scope acquire)
    if (tid == 0) {
        while (__hip_atomic_load(&g_done, __ATOMIC_ACQUIRE,
                                 __HIP_MEMORY_SCOPE_AGENT) < NBLK) {}
    }
    __syncthreads();

    // ent task: this block handles (b, c=yb); thread t owns bin t
    const int c = yb;
    const int t = tid;
    const uint2* sp = g_pk + (size_t)b * NYB * BINS + c * NLEV + t;
    unsigned cnt = 0, fq = 0;
#pragma unroll
    for (int y = 0; y < NYB; ++y) {
        uint2 v = sp[(size_t)y * BINS];
        cnt += v.x;
        fq  += v.y;
    }
    __shared__ unsigned fsb[NLEV];
    __shared__ unsigned dsh;
    fsb[t] = fq;
    if (t < 64) {   // parallel drop-sum over 64 y-blocks (full wave)
        unsigned d = g_dropQ[(b * NYB + t) * NC + c];
#pragma unroll
        for (int o = 32; o > 0; o >>= 1) d += __shfl_down(d, o);
        if (t == 0) dsh = d;
    }
    __syncthreads();
    // pass-in from previous bin; bin 0 receives bin 255's frac minus dropped
    unsigned passq = (t == 0) ? (fsb[NLEV - 1] - dsh) : fsb[t - 1];
    float hist = (float)cnt + ((float)passq - (float)fq) * (1.0f / 1024.0f);
    float pr = hist * (1.0f / (float)(IMG_H * IMG_W));
    float term = (pr > 0.0f) ? -pr * log2f(pr) : 0.0f;
#pragma unroll
    for (int o = 32; o > 0; o >>= 1) term += __shfl_down(term, o);
    __shared__ float red[4];
    if ((t & 63) == 0) red[t >> 6] = term;
    __syncthreads();
    if (t == 0) {
        g_ent[b * NC + c] = red[0] + red[1] + red[2] + red[3];
        __threadfence();                           // release g_ent
        unsigned prev = atomicAdd(&g_done2, 1u);
        if (prev == NB * NC - 1) {                 // last ent block finishes
            __threadfence();                       // acquire g_ent
            float s = 0.0f;
            for (int i = 0; i < NB * NC; ++i) s += g_ent[i];   // fixed order
            out[0] = s * (1.0f / (float)(NB * NC) / 8.0f);
            g_done = 0;                            // reset for next replay
            g_done2 = 0;
        }
    }
}

extern "C" void kernel_launch(void* const* d_in, const int* in_sizes, int n_in,
                              void* d_out, int out_size, void* d_ws, size_t ws_size,
                              hipStream_t stream) {
    const float* x = (const float*)d_in[0];
    const float* params = (const float*)d_in[1];
    float* out = (float*)d_out;

    dim3 grid(NB, NYB);   // 32 x 64
    hist_ent<<<grid, NTHR, 0, stream>>>(x, params, out);
}

// Round 13
// 41.108 us; speedup vs baseline: 6.2477x; 6.2477x over previous
//
#include <hip/hip_runtime.h>

#define IMG_H 512
#define IMG_W 512
#define RPB 8             // rows per block
#define NROW (RPB + 1)    // 9 (incl. north halo)
#define NLEV 256
#define NB 32
#define NC 3
#define NYB (IMG_H / RPB) // 64
#define BINS (NC * NLEV)  // 768
#define NBLK (NB * NYB)   // 2048
#define NTHR 256
#define NWAVE (NTHR / 64) // 4

// Accumulated per-(b,c,bin) packed {cnt:32|fq:32}: u64 atomics, 192 KB.
// Zero at module load; ent_kernel self-resets after reading (graph replay).
__device__ unsigned long long g_acc[NB * NC * NLEV];
__device__ unsigned g_dropA[NB * NC];      // dropped frac (i0==255), per (b,c)
__device__ float    g_ent[NB * NC];
__device__ unsigned g_done = 0;            // ent-completion counter (self-resetting)

// fmodf(v+1,2)-1, branch-free, exact.
__device__ __forceinline__ float wrap1(float v) {
    float a = v + 1.0f;
    return a - 2.0f * truncf(0.5f * a) - 1.0f;
}

__device__ __forceinline__ void xform(float& r, float& g, float& bl,
                                      const float* __restrict__ p) {
    float r1 = r + (p[0] * g + p[1] * bl);
    float g1 = g + (p[2] * r1 + p[3] * bl);
    float b1 = bl + (p[4] * r1 + p[5] * g1);
    float r2 = r1 + (p[6] * g1 + p[7] * b1);
    float g2 = g1 + (p[8] * r2 + p[9] * b1);
    float b2 = b1 + (p[10] * r2 + p[11] * g2);
    r = wrap1(r2); g = wrap1(g2); bl = wrap1(b2);
}

// Residual -> ONE packed u32 LDS atomic: {count:11 | fracQ:21}. JAX
// negative-index wrap (+256) before bounds check. Drop (i0==255 frac)
// accumulates in a REGISTER (no inner-loop atomic / exec-mask dance).
__device__ __forceinline__ void accum(float y, float n, float w, float nw,
                                      unsigned* __restrict__ h,
                                      unsigned& drop) {
    float lo = fminf(n, w), hi = fmaxf(n, w);
    float pred = fminf(fmaxf(n + w - nw, lo), hi);
    float xs = (y - pred + 1.0f) * 127.5f;
    float f = floorf(xs);
    float frac = xs - f;
    int i0 = (int)f;
    unsigned fq = (unsigned)(frac * 1024.0f + 0.5f);
    int j0 = (i0 < 0) ? i0 + NLEV : i0;
    if ((unsigned)j0 < (unsigned)NLEV) {
        atomicAdd(&h[j0], (1u << 21) | fq);
    }
    drop += (i0 == NLEV - 1) ? fq : 0u;    // i0==255 implies in-range
}

__global__ __launch_bounds__(NTHR) void hist_kernel(const float* __restrict__ x,
                                                    const float* __restrict__ params) {
    __shared__ unsigned lhw[NWAVE][NC][NLEV];  // 12 KiB packed hists
    __shared__ float bnd[NWAVE][NROW][NC];     // lane-63 odd-col y per wave
    __shared__ unsigned dropw[NC];
    const int tid = threadIdx.x;
    const int b = blockIdx.x;
    const int yb = blockIdx.y;
    const int r0 = yb * RPB;
    const int wv = tid >> 6;
    const int lane = tid & 63;

    unsigned* lp = &lhw[0][0][0];
#pragma unroll
    for (int i = tid; i < NWAVE * BINS; i += NTHR) lp[i] = 0u;
    if (tid < NC) dropw[tid] = 0u;

    float p[12];
#pragma unroll
    for (int i = 0; i < 12; ++i) p[i] = params[i];

    const int hw = IMG_H * IMG_W;
    // thread owns cols {2*tid, 2*tid+1}; float2 units
    const float2* base = (const float2*)(x + (size_t)(b * 3) * hw) + tid;

    // Phase A: 27 independent float2 loads
    float a0[NROW], a1[NROW], c0[NROW], c1[NROW], e0[NROW], e1[NROW];
#pragma unroll
    for (int rr = 0; rr < NROW; ++rr) {
        if (rr > 0 || r0 > 0) {
            int ro = (r0 - 1 + rr) * (IMG_W / 2);
            float2 vr = base[ro];
            float2 vg = base[ro + hw / 2];
            float2 vb = base[ro + hw];
            a0[rr] = vr.x; a1[rr] = vr.y;
            c0[rr] = vg.x; c1[rr] = vg.y;
            e0[rr] = vb.x; e1[rr] = vb.y;
        } else {
            a0[rr] = a1[rr] = c0[rr] = c1[rr] = e0[rr] = e1[rr] = 0.0f;
        }
    }

    // Phase B: transform both columns, all rows (transform(0)==0)
#pragma unroll
    for (int rr = 0; rr < NROW; ++rr) {
        xform(a0[rr], c0[rr], e0[rr], p);
        xform(a1[rr], c1[rr], e1[rr], p);
    }

    // boundary: lane 63's odd col feeds next wave's lane 0
    if (lane == 63) {
#pragma unroll
        for (int rr = 0; rr < NROW; ++rr) {
            bnd[wv][rr][0] = a1[rr];
            bnd[wv][rr][1] = c1[rr];
            bnd[wv][rr][2] = e1[rr];
        }
    }
    __syncthreads();

    // stage prev wave's 27 boundary words with ONE ds_read; extract via
    // v_readlane (compile-time lane index) -> zero DS reads in the loop.
    const int pw = (wv > 0) ? wv - 1 : 0;
    const float* pwb = &bnd[pw][0][0];
    float bv = pwb[lane < NROW * NC ? lane : 0];
    const bool lz = (lane == 0);

#define RDL(rr, ch) __int_as_float(__builtin_amdgcn_readlane(__float_as_int(bv), (rr) * NC + (ch)))

    unsigned* h0 = &lhw[wv][0][0];
    unsigned* h1 = &lhw[wv][1][0];
    unsigned* h2 = &lhw[wv][2][0];
    unsigned dr0 = 0u, dr1 = 0u, dr2 = 0u;   // register drop accumulators

    // carries: north (both cols) + northwest (even col; nw of odd = n of even)
    float nA0 = a0[0], nA1 = a1[0];
    float nC0 = c0[0], nC1 = c1[0];
    float nE0 = e0[0], nE1 = e1[0];
    float nwA = __shfl_up(a1[0], 1);
    float nwC = __shfl_up(c1[0], 1);
    float nwE = __shfl_up(e1[0], 1);
    {
        float bA = (wv > 0) ? RDL(0, 0) : 0.0f;
        float bC = (wv > 0) ? RDL(0, 1) : 0.0f;
        float bE = (wv > 0) ? RDL(0, 2) : 0.0f;
        if (lz) { nwA = bA; nwC = bC; nwE = bE; }
    }

#pragma unroll
    for (int rr = 1; rr < NROW; ++rr) {
        float uA0 = a0[rr], uA1 = a1[rr];
        float uC0 = c0[rr], uC1 = c1[rr];
        float uE0 = e0[rr], uE1 = e1[rr];
        float vA = __shfl_up(uA1, 1);
        float vC = __shfl_up(uC1, 1);
        float vE = __shfl_up(uE1, 1);
        float bA = (wv > 0) ? RDL(rr, 0) : 0.0f;
        float bC = (wv > 0) ? RDL(rr, 1) : 0.0f;
        float bE = (wv > 0) ? RDL(rr, 2) : 0.0f;
        if (lz) { vA = bA; vC = bC; vE = bE; }
        // even col: west = vX, nw = nwX ; odd col: west = even cur, nw = even north
        accum(uA0, nA0, vA, nwA, h0, dr0);
        accum(uA1, nA1, uA0, nA0, h0, dr0);
        accum(uC0, nC0, vC, nwC, h1, dr1);
        accum(uC1, nC1, uC0, nC0, h1, dr1);
        accum(uE0, nE0, vE, nwE, h2, dr2);
        accum(uE1, nE1, uE0, nE0, h2, dr2);
        nwA = vA; nA0 = uA0; nA1 = uA1;
        nwC = vC; nC0 = uC0; nC1 = uC1;
        nwE = vE; nE0 = uE0; nE1 = uE1;
    }

    // wave-reduce drops, one LDS add per wave per channel
#pragma unroll
    for (int o = 32; o > 0; o >>= 1) {
        dr0 += __shfl_down(dr0, o);
        dr1 += __shfl_down(dr1, o);
        dr2 += __shfl_down(dr2, o);
    }
    if (lz) {
        atomicAdd(&dropw[0], dr0);
        atomicAdd(&dropw[1], dr1);
        atomicAdd(&dropw[2], dr2);
    }
    __syncthreads();

    // flush: unpack + sum 4 waves, ONE u64 global atomic per bin.
    // Per (b,c,bin): cnt <= 2^18, fq <= 2^28 -> fields never carry.
    const int gb = b * NC;
#pragma unroll
    for (int i = tid; i < BINS; i += NTHR) {
        int c = i >> 8, bin = i & 255;
        unsigned cs = 0, qs = 0;
#pragma unroll
        for (int w2 = 0; w2 < NWAVE; ++w2) {
            unsigned v = lhw[w2][c][bin];
            cs += v >> 21;
            qs += v & 0x1FFFFFu;
        }
        atomicAdd(&g_acc[(gb + c) * NLEV + bin],
                  ((unsigned long long)cs << 32) | (unsigned long long)qs);
    }
    if (tid < NC) atomicAdd(&g_dropA[gb + tid], dropw[tid]);
}

// Entropy: one block per (b,c); thread t owns bin t. Read accumulated
// {cnt,fq}, self-reset to zero (exactly one reader per slot -> safe,
// deterministic, keeps g_acc==0 invariant for graph replays).
__global__ __launch_bounds__(256) void ent_kernel(float* __restrict__ out) {
    const int g = blockIdx.x;          // b*NC + c
    const int t = threadIdx.x;         // bin
    unsigned long long v = g_acc[(size_t)g * NLEV + t];
    g_acc[(size_t)g * NLEV + t] = 0ull;
    unsigned cnt = (unsigned)(v >> 32);
    unsigned fq  = (unsigned)(v & 0xFFFFFFFFull);
    __shared__ unsigned fsb[NLEV];
    __shared__ unsigned dsh;
    fsb[t] = fq;
    if (t == 0) { dsh = g_dropA[g]; g_dropA[g] = 0u; }
    __syncthreads();
    // pass-in from previous bin; bin 0 receives bin 255's frac minus dropped
    unsigned passq = (t == 0) ? (fsb[NLEV - 1] - dsh) : fsb[t - 1];
    float hist = (float)cnt + ((float)passq - (float)fq) * (1.0f / 1024.0f);
    float pr = hist * (1.0f / (float)(IMG_H * IMG_W));
    float term = (pr > 0.0f) ? -pr * log2f(pr) : 0.0f;
#pragma unroll
    for (int o = 32; o > 0; o >>= 1) term += __shfl_down(term, o);
    __shared__ float red[4];
    if ((t & 63) == 0) red[t >> 6] = term;
    __syncthreads();
    if (t == 0) {
        g_ent[g] = red[0] + red[1] + red[2] + red[3];
        __threadfence();                            // release g_ent
        unsigned prev = atomicAdd(&g_done, 1u);
        if (prev == NB * NC - 1) {                  // last ent block finishes
            __threadfence();                        // acquire g_ent
            float s = 0.0f;
            for (int i = 0; i < NB * NC; ++i) s += g_ent[i];   // fixed order
            out[0] = s * (1.0f / (float)(NB * NC) / 8.0f);
            g_done = 0;                             // reset for next replay
        }
    }
}

extern "C" void kernel_launch(void* const* d_in, const int* in_sizes, int n_in,
                              void* d_out, int out_size, void* d_ws, size_t ws_size,
                              hipStream_t stream) {
    const float* x = (const float*)d_in[0];
    const float* params = (const float*)d_in[1];
    float* out = (float*)d_out;

    dim3 grid(NB, NYB);   // 32 x 64
    hist_kernel<<<grid, NTHR, 0, stream>>>(x, params);
    ent_kernel<<<NB * NC, 256, 0, stream>>>(out);
}